// Round 3
// baseline (84.203 us; speedup 1.0000x reference)
//
#include <hip/hip_runtime.h>
#include <math.h>

#define N      4096
#define BLOCK  256                 // one j per thread
#define ISEG   32                  // i-rows per block
#define NJT    (N / BLOCK)         // 16 j-tiles
#define NTILE  1088                // sum_{J=0..15} (8J+8) = 4*16*17

// s(e) = sum_k 1/(1 + c_k*e), c_k = e^{-t_k}, t = {0.5,1,2,4} = Pn(e)/Pd(e)
#define PN0 4.0f
#define PN1 3.384183069f
#define PN2 0.750655861f
#define PN3 0.036699475f
#define PD1 1.128061023f
#define PD2 0.375327930f
#define PD3 0.036699475f
#define PD4 0.000553084f

__device__ __forceinline__ int tile_off(int J) { return 4 * J * (J + 1); }

// NOTE (prev session): do NOT fuse the final reduction via global atomics +
// ticket: serialized wave-0s cost ~75 us. Per-block stores + finalize wins.
// NOTE (R1 post-mortem): depth-1 SW pipeline of LDS broadcast reads
// REGRESSED (+6.4us) -> LDS latency was not the issue.
// NOTE (R2 post-mortem): eliminating LDS entirely (j per-lane in VGPRs,
// i uniform via s_load) was NEUTRAL (82.5 vs 81.4): main ~28us under BOTH
// structures -> stall source is interchangeable, limiter is occupancy.
// VALUBusy arithmetic: 8704 waves x ~1740 cyc = 15.1M busy vs 68.8M
// available SIMD-cycles in 28us => ~22% VALU. Latency-bound at 4 waves/SIMD.
// NOTE (this round): single-variable A/B vs R2 -> __launch_bounds__(256,8):
// VGPR cap 64 (R2 structure is lean: ~10 persistent + ~30 transient VGPRs,
// uniform ptrs/indices in SGPRs), 8 blocks/CU, 2048/2176 blocks resident.
__global__ __launch_bounds__(BLOCK, 8) void lddt_main_kernel(
    const float* __restrict__ pred, const float* __restrict__ truec,
    const int* __restrict__ is_dna, const int* __restrict__ is_rna,
    const int* __restrict__ cmask, float* __restrict__ ws)
{
    const int L     = blockIdx.x;     // 0..NTILE-1, linear tile id
    const int batch = blockIdx.z;
    const int tid   = threadIdx.x;

    int J = 0;
#pragma unroll
    for (int u = 1; u < NJT; ++u) J += (L >= tile_off(u)) ? 1 : 0;
    const int S    = L - tile_off(J);        // i-seg, in [0, 8J+8)
    const bool diag = (S >= 8 * J);          // i-range overlaps j-range
    const int i0   = S * ISEG;
    const int j0   = J * BLOCK;
    const int j    = j0 + tid;               // this thread's j (per-lane)

    const float* pb = pred  + (size_t)batch * N * 3;
    const float* tb = truec + (size_t)batch * N * 3;
    const int* dnab = is_dna + (size_t)batch * N;
    const int* rnab = is_rna + (size_t)batch * N;
    const int* cmb  = cmask  + (size_t)batch * N;

    // per-lane j-data, loaded once (coalesced: 64 lanes x 12B contiguous)
    const float pjx = pb[j*3+0], pjy = pb[j*3+1], pjz = pb[j*3+2];
    const float tjx = tb[j*3+0], tjy = tb[j*3+1], tjz = tb[j*3+2];
    const float cutA = (dnab[j] | rnab[j]) ? 900.0f : 225.0f;  // 30^2 : 15^2
    const float cjw  = cmb[j] ? 1.0f : 0.0f;

    float num = 0.0f, den = 0.0f;

    // One i (uniform): i-row scalars come from SGPRs (s_load). Each VALU
    // inst reads <=1 SGPR operand (ISA-legal). cm_i/nuc_i fold into cutl:
    // cutl = -1 when cm_i==0 -> d2t < cutl never true -> m=0.
#define IBODY(IDX, NEED_TRI, TT, NDOUT)                                        \
    {                                                                          \
        const int i = i0 + (IDX);                                              \
        const float six = pb[i*3+0], siy = pb[i*3+1], siz = pb[i*3+2];         \
        const float tix = tb[i*3+0], tiy = tb[i*3+1], tiz = tb[i*3+2];         \
        const bool nuci = (dnab[i] | rnab[i]) != 0;                            \
        const bool cmi  = cmb[i] != 0;                                         \
        float dxp = pjx - six, dyp = pjy - siy, dzp = pjz - siz;               \
        float d2p = dxp*dxp + dyp*dyp + dzp*dzp;                               \
        float dxt = tjx - tix, dyt = tjy - tiy, dzt = tjz - tiz;               \
        float d2t = dxt*dxt + dyt*dyt + dzt*dzt;                               \
        float dpv = __builtin_amdgcn_sqrtf(d2p);                               \
        float dtv = __builtin_amdgcn_sqrtf(d2t);                               \
        float e   = __expf(fminf(fabsf(dtv - dpv), 10.0f));                    \
        float NNv = ((e * PN3 + PN2) * e + PN1) * e + PN0;                     \
        NDOUT = (((e * PD4 + PD3) * e + PD2) * e + PD1) * e + 1.0f;            \
        float cutl = cmi ? (nuci ? cutA : 225.0f) : -1.0f;                     \
        bool k = d2t < cutl;                                                   \
        if (NEED_TRI) k = k && (j > i);                                        \
        float m = k ? cjw : 0.0f;                                              \
        den += m;                                                              \
        TT = m * NNv;                                                          \
    }

    // two i's per step share one rcp (same trick as before, across i now)
#define ILOOP(NEED_TRI)                                                        \
    _Pragma("unroll 2")                                                        \
    for (int ii = 0; ii < ISEG; ii += 2) {                                     \
        float t0, t1, nd0, nd1;                                                \
        IBODY(ii,     NEED_TRI, t0, nd0)                                       \
        IBODY(ii + 1, NEED_TRI, t1, nd1)                                       \
        float na = fmaf(t0, nd1, t1 * nd0);                                    \
        num = fmaf(na, __builtin_amdgcn_rcpf(nd0 * nd1), num);                 \
    }

    if (diag) {
        ILOOP(true)
    } else {
        ILOOP(false)
    }
#undef ILOOP
#undef IBODY

    // symmetry x2, threshold-mean /4  (cm_i folded into cutl, cm_j in cjw)
    num *= 0.5f;
    den *= 2.0f;

    for (int off = 32; off > 0; off >>= 1) {
        num += __shfl_down(num, off);
        den += __shfl_down(den, off);
    }
    __shared__ float rn[BLOCK / 64], rd[BLOCK / 64];
    const int wid = tid >> 6, lane = tid & 63;
    if (lane == 0) { rn[wid] = num; rd[wid] = den; }
    __syncthreads();
    if (tid == 0) {
        float tn = rn[0] + rn[1] + rn[2] + rn[3];
        float td = rd[0] + rd[1] + rd[2] + rd[3];
        const int bid = batch * NTILE + L;
        ws[bid * 2 + 0] = tn;   // plain stores to distinct slots -> no init,
        ws[bid * 2 + 1] = td;   // no atomics, no fence
    }
}

// finalize: known-good R0 version (4 waves, LDS combine)
__global__ __launch_bounds__(BLOCK) void finalize_kernel(
    const float* __restrict__ ws, float* __restrict__ out, int b)
{
    __shared__ float sn[4], sd[4];
    float acc = 0.0f;
    for (int k = 0; k < b; ++k) {
        float n = 0.0f, d = 0.0f;
        for (int p = threadIdx.x; p < NTILE; p += BLOCK) {
            n += ws[(k * NTILE + p) * 2 + 0];
            d += ws[(k * NTILE + p) * 2 + 1];
        }
        for (int off = 32; off > 0; off >>= 1) {
            n += __shfl_down(n, off);
            d += __shfl_down(d, off);
        }
        if ((threadIdx.x & 63) == 0) { sn[threadIdx.x >> 6] = n; sd[threadIdx.x >> 6] = d; }
        __syncthreads();
        if (threadIdx.x == 0) {
            float tn = sn[0] + sn[1] + sn[2] + sn[3];
            float td = sd[0] + sd[1] + sd[2] + sd[3];
            acc += tn / fmaxf(td, 1.0f);
        }
        __syncthreads();
    }
    if (threadIdx.x == 0) out[0] = 1.0f - acc / (float)b;
}

extern "C" void kernel_launch(void* const* d_in, const int* in_sizes, int n_in,
                              void* d_out, int out_size, void* d_ws, size_t ws_size,
                              hipStream_t stream) {
    const float* pred  = (const float*)d_in[0];
    const float* truec = (const float*)d_in[1];
    const int* is_dna  = (const int*)d_in[2];
    const int* is_rna  = (const int*)d_in[3];
    const int* cmask   = (const int*)d_in[4];
    float* out = (float*)d_out;
    float* ws  = (float*)d_ws;

    const int b = in_sizes[2] / N;

    dim3 grid(NTILE, 1, b);   // 1088 x b = 2176 blocks
    lddt_main_kernel<<<grid, BLOCK, 0, stream>>>(pred, truec, is_dna, is_rna, cmask, ws);
    finalize_kernel<<<1, BLOCK, 0, stream>>>(ws, out, b);
}